// Round 4
// baseline (211.651 us; speedup 1.0000x reference)
//
#include <hip/hip_runtime.h>
#include <hip/hip_bf16.h>

#define BB 16
#define SS 4096
#define DD 512

// Kernel 1: per batch row, compute keep flags, stable exclusive scan,
// scatter compacted source indices, write per-row count.
__global__ __launch_bounds__(1024) void skipper_scan_kernel(
    const float* __restrict__ probs, const float* __restrict__ uni,
    int* __restrict__ src_idx, int* __restrict__ counts) {
  const int b = blockIdx.x;
  const int t = threadIdx.x;          // 0..1023
  const int s0 = t * 4;               // 4 contiguous elements per thread
  const float4 p = *reinterpret_cast<const float4*>(probs + b * SS + s0);
  const float4 u = *reinterpret_cast<const float4*>(uni + b * SS + s0);
  const int k0 = (u.x >= p.x) ? 1 : 0;
  const int k1 = (u.y >= p.y) ? 1 : 0;
  const int k2 = (u.z >= p.z) ? 1 : 0;
  const int k3 = (u.w >= p.w) ? 1 : 0;
  const int mysum = k0 + k1 + k2 + k3;

  const int lane = t & 63;
  const int wave = t >> 6;            // 0..15

  // wave-inclusive scan (64 lanes)
  int incl = mysum;
  #pragma unroll
  for (int off = 1; off < 64; off <<= 1) {
    int v = __shfl_up(incl, off, 64);
    if (lane >= off) incl += v;
  }

  __shared__ int wave_tot[16];
  __shared__ int wave_off[16];
  if (lane == 63) wave_tot[wave] = incl;
  __syncthreads();
  if (t < 16) {
    int v = wave_tot[t];
    int inc = v;
    #pragma unroll
    for (int off = 1; off < 16; off <<= 1) {
      int w = __shfl_up(inc, off, 64);
      if (t >= off) inc += w;
    }
    wave_off[t] = inc - v;            // exclusive wave offset
    if (t == 15) counts[b] = inc;     // total kept in this row
  }
  __syncthreads();

  int r = wave_off[wave] + (incl - mysum);  // exclusive prefix for s0
  const int base = b * SS;
  if (k0) { src_idx[base + r] = s0;     r += 1; }
  if (k1) { src_idx[base + r] = s0 + 1; r += 1; }
  if (k2) { src_idx[base + r] = s0 + 2; r += 1; }
  if (k3) { src_idx[base + r] = s0 + 3; r += 1; }
}

// Kernel 2: fixed-tile gather with 8 independent load chains per thread.
// Each block owns 2048 consecutive float4 slots (256 threads x 8).
// Load loop issues all src_idx->x chains before the store loop: 16
// outstanding loads per thread to hide scattered-2KiB-row read latency.
__global__ __launch_bounds__(256) void skipper_gather_kernel(
    const float* __restrict__ x, const int* __restrict__ src_idx,
    const int* __restrict__ counts, float* __restrict__ padded,
    float* __restrict__ mask, int max_len, int total4) {
  const float4* __restrict__ x4 = reinterpret_cast<const float4*>(x);
  float4* __restrict__ p4 = reinterpret_cast<float4*>(padded);
  const int t = threadIdx.x;
  const int iBase = blockIdx.x * 2048 + t;

  float4 v[8];
  int   iArr[8];
  int   bjArr[8];
  bool  inb[8];
  bool  keepMask[8];

  #pragma unroll
  for (int u = 0; u < 8; ++u) {
    const int i = iBase + (u << 8);
    inb[u] = (i < total4);
    const int ic = inb[u] ? i : 0;     // clamp OOB lanes to a safe slot
    iArr[u] = ic;
    const int d  = ic & 127;
    const int bj = ic >> 7;
    bjArr[u] = bj;
    const int b  = bj / max_len;
    const int j  = bj - b * max_len;
    const int cnt = counts[b];
    const bool keep = (j < cnt);
    keepMask[u] = keep;
    float4 val = make_float4(0.f, 0.f, 0.f, 0.f);
    if (keep) {
      const int s = src_idx[(b << 12) + j];
      val = x4[(((size_t)(b << 12)) + s) * 128 + d];
    }
    v[u] = val;
  }

  #pragma unroll
  for (int u = 0; u < 8; ++u) {
    if (inb[u]) {
      p4[(size_t)iArr[u]] = v[u];
      if ((iArr[u] & 127) == 0)
        mask[bjArr[u]] = keepMask[u] ? 1.0f : 0.0f;
    }
  }
}

extern "C" void kernel_launch(void* const* d_in, const int* in_sizes, int n_in,
                              void* d_out, int out_size, void* d_ws, size_t ws_size,
                              hipStream_t stream) {
  const float* x     = (const float*)d_in[0];
  const float* probs = (const float*)d_in[1];
  const float* uni   = (const float*)d_in[2];

  // out_size = B*max_len*D + B*max_len = B*max_len*(D+1)
  const int max_len = out_size / (BB * (DD + 1));

  int* src_idx = (int*)d_ws;               // B*S ints = 256 KiB
  int* counts  = src_idx + BB * SS;        // 16 ints

  float* padded = (float*)d_out;                       // B*max_len*D
  float* mask   = padded + (size_t)BB * max_len * DD;  // B*max_len

  skipper_scan_kernel<<<BB, 1024, 0, stream>>>(probs, uni, src_idx, counts);

  const int total4 = BB * max_len * (DD / 4);          // float4 slots
  const int blocks = (total4 + 2047) / 2048;           // 2048 float4 per block
  skipper_gather_kernel<<<blocks, 256, 0, stream>>>(
      x, src_idx, counts, padded, mask, max_len, total4);
}

// Round 5
// 204.509 us; speedup vs baseline: 1.0349x; 1.0349x over previous
//
#include <hip/hip_runtime.h>
#include <hip/hip_bf16.h>

#define BB 16
#define SS 4096
#define DD 512

// Kernel 1: per batch row, compute keep flags, stable exclusive scan,
// scatter compacted source indices, write per-row count.
__global__ __launch_bounds__(1024) void skipper_scan_kernel(
    const float* __restrict__ probs, const float* __restrict__ uni,
    int* __restrict__ src_idx, int* __restrict__ counts) {
  const int b = blockIdx.x;
  const int t = threadIdx.x;          // 0..1023
  const int s0 = t * 4;               // 4 contiguous elements per thread
  const float4 p = *reinterpret_cast<const float4*>(probs + b * SS + s0);
  const float4 u = *reinterpret_cast<const float4*>(uni + b * SS + s0);
  const int k0 = (u.x >= p.x) ? 1 : 0;
  const int k1 = (u.y >= p.y) ? 1 : 0;
  const int k2 = (u.z >= p.z) ? 1 : 0;
  const int k3 = (u.w >= p.w) ? 1 : 0;
  const int mysum = k0 + k1 + k2 + k3;

  const int lane = t & 63;
  const int wave = t >> 6;            // 0..15

  // wave-inclusive scan (64 lanes)
  int incl = mysum;
  #pragma unroll
  for (int off = 1; off < 64; off <<= 1) {
    int v = __shfl_up(incl, off, 64);
    if (lane >= off) incl += v;
  }

  __shared__ int wave_tot[16];
  __shared__ int wave_off[16];
  if (lane == 63) wave_tot[wave] = incl;
  __syncthreads();
  if (t < 16) {
    int v = wave_tot[t];
    int inc = v;
    #pragma unroll
    for (int off = 1; off < 16; off <<= 1) {
      int w = __shfl_up(inc, off, 64);
      if (t >= off) inc += w;
    }
    wave_off[t] = inc - v;            // exclusive wave offset
    if (t == 15) counts[b] = inc;     // total kept in this row
  }
  __syncthreads();

  int r = wave_off[wave] + (incl - mysum);  // exclusive prefix for s0
  const int base = b * SS;
  if (k0) { src_idx[base + r] = s0;     r += 1; }
  if (k1) { src_idx[base + r] = s0 + 1; r += 1; }
  if (k2) { src_idx[base + r] = s0 + 2; r += 1; }
  if (k3) { src_idx[base + r] = s0 + 3; r += 1; }
}

// Kernel 2: one block per output slot (b, j). 128 threads x float4 = 512 floats.
// Measured best of three structural variants (205.2 vs 206.6 / 211.7 us):
// tiny blocks give the scheduler maximal freedom; gather is BW-floor-bound.
__global__ __launch_bounds__(128) void skipper_gather_kernel(
    const float* __restrict__ x, const int* __restrict__ src_idx,
    const int* __restrict__ counts, float* __restrict__ padded,
    float* __restrict__ mask, int max_len) {
  const int blk = blockIdx.x;
  const int b = blk / max_len;
  const int j = blk - b * max_len;
  const int t = threadIdx.x;          // 0..127
  const int cnt = counts[b];

  float4 v = make_float4(0.f, 0.f, 0.f, 0.f);
  if (j < cnt) {
    const int s = src_idx[b * SS + j];
    v = *reinterpret_cast<const float4*>(x + ((size_t)(b * SS + s)) * DD + t * 4);
  }
  *reinterpret_cast<float4*>(padded + ((size_t)(b * max_len + j)) * DD + t * 4) = v;
  if (t == 0) mask[b * max_len + j] = (j < cnt) ? 1.0f : 0.0f;
}

extern "C" void kernel_launch(void* const* d_in, const int* in_sizes, int n_in,
                              void* d_out, int out_size, void* d_ws, size_t ws_size,
                              hipStream_t stream) {
  const float* x     = (const float*)d_in[0];
  const float* probs = (const float*)d_in[1];
  const float* uni   = (const float*)d_in[2];

  // out_size = B*max_len*D + B*max_len = B*max_len*(D+1)
  const int max_len = out_size / (BB * (DD + 1));

  int* src_idx = (int*)d_ws;               // B*S ints = 256 KiB
  int* counts  = src_idx + BB * SS;        // 16 ints

  float* padded = (float*)d_out;                       // B*max_len*D
  float* mask   = padded + (size_t)BB * max_len * DD;  // B*max_len

  skipper_scan_kernel<<<BB, 1024, 0, stream>>>(probs, uni, src_idx, counts);
  skipper_gather_kernel<<<BB * max_len, 128, 0, stream>>>(
      x, src_idx, counts, padded, mask, max_len);
}